// Round 1
// baseline (589.599 us; speedup 1.0000x reference)
//
#include <hip/hip_runtime.h>
#include <math.h>

// Problem constants (from reference)
#define BB 16
#define LL 100
#define TT 50
#define TE 100
#define HH 200
#define HP 256          // padded H stride for transposed weights in workspace
#define NEG_INF_F (-1e30f)

// Build WT[p][d][h] = W_p[h][d], zero-padded for h in [HH, HP).
__global__ void wt_transpose_kernel(const float* __restrict__ Wh,
                                    const float* __restrict__ Wr,
                                    const float* __restrict__ Wt,
                                    float* __restrict__ WT) {
    int idx = blockIdx.x * 256 + threadIdx.x;
    const int per = TE * HP;
    if (idx >= 3 * per) return;
    int p = idx / per;
    int rem = idx - p * per;
    int d = rem / HP;
    int h = rem - d * HP;
    const float* W = (p == 0) ? Wh : (p == 1) ? Wr : Wt;
    WT[idx] = (h < HH) ? W[h * TE + d] : 0.0f;
}

__global__ __launch_bounds__(256)
void ccm_main_kernel(const float* __restrict__ head,
                     const float* __restrict__ rel,
                     const float* __restrict__ tail,
                     const float* __restrict__ WT,   // [3][TE][HP]
                     const float* __restrict__ bh,
                     const float* __restrict__ br,
                     const float* __restrict__ bt,
                     const int* __restrict__ tmask,  // [BB*LL*TT]
                     const int* __restrict__ pmask,  // [BB*LL]
                     float* __restrict__ out) {      // [BB*LL][2*TE]
    __shared__ float sh[TT][TE];
    __shared__ float sr[TT][TE];
    __shared__ float st[TT][TE];
    __shared__ float wred[4][TT];
    __shared__ float sattn[TT];

    const int bl = blockIdx.x;      // (b,l) flat
    const int tid = threadIdx.x;

    // ---- phase 1: stage embeddings for this (b,l) into LDS (float4) ----
    {
        const int NV = TT * TE / 4;  // 1250 float4 per projection
        const float4* hs = (const float4*)(head + (size_t)bl * TT * TE);
        const float4* rs = (const float4*)(rel  + (size_t)bl * TT * TE);
        const float4* ts = (const float4*)(tail + (size_t)bl * TT * TE);
        float4* dh = (float4*)&sh[0][0];
        float4* dr = (float4*)&sr[0][0];
        float4* dt = (float4*)&st[0][0];
        for (int i = tid; i < NV; i += 256) dh[i] = hs[i];
        for (int i = tid; i < NV; i += 256) dr[i] = rs[i];
        for (int i = tid; i < NV; i += 256) dt[i] = ts[i];
    }
    __syncthreads();

    // ---- phase 2: per-h projections + score contributions ----
    const int h = tid;              // lane owns one hidden unit
    const bool hv = (h < HH);
    const float bhv = hv ? bh[h] : 0.0f;
    const float brv = hv ? br[h] : 0.0f;
    const float btv = hv ? bt[h] : 0.0f;

    for (int g = 0; g < 2; ++g) {   // two groups of 25 triples
        const int t0 = g * 25;
        float ah[25], ar[25], at_[25];
        #pragma unroll
        for (int j = 0; j < 25; ++j) { ah[j] = 0.0f; ar[j] = 0.0f; at_[j] = 0.0f; }

        for (int dc = 0; dc < TE; dc += 4) {
            const float* wph = &WT[(0 * TE + dc) * HP + h];
            const float* wpr = &WT[(1 * TE + dc) * HP + h];
            const float* wpt = &WT[(2 * TE + dc) * HP + h];
            float wh0 = wph[0], wh1 = wph[HP], wh2 = wph[2 * HP], wh3 = wph[3 * HP];
            float wr0 = wpr[0], wr1 = wpr[HP], wr2 = wpr[2 * HP], wr3 = wpr[3 * HP];
            float wt0 = wpt[0], wt1 = wpt[HP], wt2 = wpt[2 * HP], wt3 = wpt[3 * HP];
            #pragma unroll
            for (int j = 0; j < 25; ++j) {
                float4 eh = *(const float4*)&sh[t0 + j][dc];
                float4 er = *(const float4*)&sr[t0 + j][dc];
                float4 et = *(const float4*)&st[t0 + j][dc];
                ah[j]  = fmaf(eh.w, wh3, fmaf(eh.z, wh2, fmaf(eh.y, wh1, fmaf(eh.x, wh0, ah[j]))));
                ar[j]  = fmaf(er.w, wr3, fmaf(er.z, wr2, fmaf(er.y, wr1, fmaf(er.x, wr0, ar[j]))));
                at_[j] = fmaf(et.w, wt3, fmaf(et.z, wt2, fmaf(et.y, wt1, fmaf(et.x, wt0, at_[j]))));
            }
        }

        #pragma unroll
        for (int j = 0; j < 25; ++j) {
            float c = 0.0f;
            if (hv) {
                float sH = ah[j] + bhv;
                float sT = at_[j] + btv;
                float sR = ar[j] + brv;
                c = sR * tanhf(sH + sT);
            }
            // wave-wide sum over the 64 lanes (h dimension partial)
            #pragma unroll
            for (int o = 32; o; o >>= 1) c += __shfl_xor(c, o);
            if ((tid & 63) == 0) wred[tid >> 6][t0 + j] = c;
        }
    }
    __syncthreads();

    // ---- softmax over T on one wave ----
    if (tid < 64) {
        const int t = tid;
        const bool valid = (t < TT);
        float lg = 0.0f;
        if (valid) lg = wred[0][t] + wred[1][t] + wred[2][t] + wred[3][t];
        const bool tm = valid ? (tmask[bl * TT + t] != 0) : false;
        const bool pm = (pmask[bl] != 0);
        float logit = pm ? 0.0f : (tm ? NEG_INF_F : lg);
        float mx = valid ? logit : -3.0e38f;
        #pragma unroll
        for (int o = 32; o; o >>= 1) mx = fmaxf(mx, __shfl_xor(mx, o));
        float e = valid ? expf(logit - mx) : 0.0f;
        float s = e;
        #pragma unroll
        for (int o = 32; o; o >>= 1) s += __shfl_xor(s, o);
        if (valid) sattn[t] = e / s;
    }
    __syncthreads();

    // ---- phase 3: weighted aggregation, out[bl][e] ----
    if (tid < 2 * TE) {
        const int e = tid;
        float acc = 0.0f;
        if (e < TE) {
            #pragma unroll
            for (int t = 0; t < TT; ++t) acc = fmaf(sh[t][e], sattn[t], acc);
        } else {
            const int d = e - TE;
            #pragma unroll
            for (int t = 0; t < TT; ++t) acc = fmaf(st[t][d], sattn[t], acc);
        }
        out[(size_t)bl * (2 * TE) + e] = acc;
    }
}

extern "C" void kernel_launch(void* const* d_in, const int* in_sizes, int n_in,
                              void* d_out, int out_size, void* d_ws, size_t ws_size,
                              hipStream_t stream) {
    const float* head = (const float*)d_in[0];
    const float* rel  = (const float*)d_in[1];
    const float* tail = (const float*)d_in[2];
    const float* Whw  = (const float*)d_in[3];
    const float* Whb  = (const float*)d_in[4];
    const float* Wrw  = (const float*)d_in[5];
    const float* Wrb  = (const float*)d_in[6];
    const float* Wtw  = (const float*)d_in[7];
    const float* Wtb  = (const float*)d_in[8];
    const int* tmask  = (const int*)d_in[9];
    const int* pmask  = (const int*)d_in[10];
    float* out = (float*)d_out;
    float* WT  = (float*)d_ws;   // 3 * TE * HP floats = 1.2 MB

    const int total = 3 * TE * HP;
    wt_transpose_kernel<<<(total + 255) / 256, 256, 0, stream>>>(Whw, Wrw, Wtw, WT);
    ccm_main_kernel<<<BB * LL, 256, 0, stream>>>(head, rel, tail, WT,
                                                 Whb, Wrb, Wtb, tmask, pmask, out);
}